// Round 20
// baseline (366.785 us; speedup 1.0000x reference)
//
#include <hip/hip_runtime.h>

// Hex conv:  y[h,w,f] = relu( bias[f] + sum_taps x[h+dr, w+dc, c] * K[kr,kc][c][f] )
// even h (7 taps): (dr,dc,kr,kc)=(0,0,0,1)(0,1,0,2)(1,-1,1,0)(1,0,1,1)(1,1,1,2)(2,0,2,1)(2,1,2,2)
// odd  h (4 taps): (0,-1)K01 (0,0)K02 (1,-1)K21 (1,0)K22  -> weight tiles {0,1,5,6}
// x: (16,128,128,128) fp32 NHWC; K: (3,3,128,256) fp32 HWIO; bias: (256,) fp32. out fp32.
//
// Round 20: PARITY-MERGED blocks. 512 thr / 8 waves (2w x 2f x 2parity); one
// block computes h=2*hp and 2*hp+1 for one ft. 14 steps (hc x 7 taps); odd
// waves join on taps {0,1,5,6} (same B tile as even!). A = 2 rotating halo
// slots (rows {0,1} -> {1,2} per hc; 6 stages/block). B = dbuf 2x16KB staged
// before MFMA. LDS 66KB dynamic -> 2 blocks x 8 waves = 16 waves/CU.

#define N_  16
#define H_  128
#define W_  128
#define C_  128
#define F_  256
#define HP  130
#define WP  130

#define A_TILE_B   16640          // 130 rows x 128B
#define B_SLOT_B   16384
#define B_BASE     (2 * A_TILE_B) // B0 @33280, B1 @49664; total 66048

typedef short bf16x8 __attribute__((ext_vector_type(8)));
typedef float f32x4  __attribute__((ext_vector_type(4)));

__device__ __forceinline__ unsigned int bf_bits(float f) {
  unsigned int u = __float_as_uint(f);
  return (u + 0x7FFFu + ((u >> 16) & 1u)) >> 16;   // RNE fp32 -> bf16
}
__device__ __forceinline__ unsigned int pack2(float a, float b) {
  return bf_bits(a) | (bf_bits(b) << 16);
}

__device__ __forceinline__ void even_tap(int ti, int& dr, int& dc, int& kr, int& kc) {
  switch (ti) {
    case 0:  dr = 0; dc = 0;  kr = 0; kc = 1; break;
    case 1:  dr = 0; dc = 1;  kr = 0; kc = 2; break;
    case 2:  dr = 1; dc = -1; kr = 1; kc = 0; break;
    case 3:  dr = 1; dc = 0;  kr = 1; kc = 1; break;
    case 4:  dr = 1; dc = 1;  kr = 1; kc = 2; break;
    case 5:  dr = 2; dc = 0;  kr = 2; kc = 1; break;
    default: dr = 2; dc = 1;  kr = 2; kc = 2; break;
  }
}

// ---------- prep 1: pad + bf16 x, slot key = ABSOLUTE padded column (wp&7) ----
// xpadH pixel (n,hh,wp): 256B = [hc0:128B][hc1:128B]; slot g holds channels
// ((g ^ (wp&7))*8 .. +8) + hc*64 of x(n, hh, wp-1); zero outside image.
__global__ __launch_bounds__(256) void prep_xpadH(
    const float* __restrict__ x, char* __restrict__ xp) {
  long id = (long)blockIdx.x * 256 + threadIdx.x;   // exact 4,326,400 chunks
  const int g  = (int)(id & 7);
  const int hc = (int)((id >> 3) & 1);
  long pix = id >> 4;
  const int wp = (int)(pix % WP);
  long t = pix / WP;
  const int hh = (int)(t % HP);
  const int nn = (int)(t / HP);
  const int ww = wp - 1;
  uint4 o = make_uint4(0u, 0u, 0u, 0u);
  if (hh < H_ && ww >= 0 && ww < W_) {
    const float* s = x + (((long)(nn * H_ + hh) * W_ + ww) * C_ + hc * 64 + ((g ^ (wp & 7)) * 8));
    float4 a = *(const float4*)s;
    float4 b = *(const float4*)(s + 4);
    o.x = pack2(a.x, a.y); o.y = pack2(a.z, a.w);
    o.z = pack2(b.x, b.y); o.w = pack2(b.z, b.w);
  }
  *(uint4*)(xp + id * 16) = o;
}

// ---------- prep 2: weight tiles keyed (f&7) ----------
// wt2[ti 0..6][hc 0..1][ft 0..1] = 16KB: [f 0..127][slot 0..7][16B]
__global__ __launch_bounds__(256) void prep_wt2(
    const float* __restrict__ k, char* __restrict__ wt2) {
  int id = blockIdx.x * 256 + threadIdx.x;
  if (id >= 7 * 2 * 2 * 128 * 8) return;
  const int g  = id & 7;
  const int f  = (id >> 3) & 127;
  const int ft = (id >> 10) & 1;
  const int hc = (id >> 11) & 1;
  const int ti = id >> 12;
  int dr, dc, kr, kc;
  even_tap(ti, dr, dc, kr, kc);
  const int fg = ft * 128 + f;
  const int c0 = hc * 64 + (g ^ (f & 7)) * 8;
  float v[8];
#pragma unroll
  for (int j = 0; j < 8; ++j)
    v[j] = k[((size_t)(kr * 3 + kc) * C_ + (c0 + j)) * F_ + fg];
  uint4 o;
  o.x = pack2(v[0], v[1]); o.y = pack2(v[2], v[3]);
  o.z = pack2(v[4], v[5]); o.w = pack2(v[6], v[7]);
  *(uint4*)(wt2 + (size_t)id * 16) = o;
}

// ---------- main: parity-merged 128(w) x 128(f) x 2(h), 8 waves ----------
__global__ __launch_bounds__(512, 4) void hconv_mfma(
    const char* __restrict__ xpadH,
    const char* __restrict__ wt2,
    const float* __restrict__ bias,
    float* __restrict__ out) {
  extern __shared__ __align__(16) char smem[];   // 66048

  const int tid = threadIdx.x;
  const int bid = (blockIdx.x & 7) * 256 + (blockIdx.x >> 3);   // 2048 = 8*256
  const int ft = bid & 1;
  const int hp = (bid >> 1) & 63;   // h-pair: h in {2hp, 2hp+1}
  const int n  = bid >> 7;

  const int lane = tid & 63;
  const int wid  = tid >> 6;        // 0..7
  const int par  = wid >> 2;        // 0 = even h, 1 = odd h
  const int wr   = (wid >> 1) & 1;  // w half
  const int wc   = wid & 1;         // f half
  const int l16  = lane & 15;
  const int lk   = lane >> 4;

  // stage A halo tile (x-row 2hp+row, channel-half hc) into slot (0 or 1)
  auto stageA = [&](int row, int hc, int slot) {
    const long pixb = (long)(n * HP + (2 * hp + row)) * WP;
    char* base = (char*)smem + slot * A_TILE_B;
#pragma unroll
    for (int i = 0; i < 3; ++i) {
      const int L = i * 512 + tid;
      if (L < 1040) {
        const int wp = L >> 3, g = L & 7;
        const char* src = xpadH + ((pixb + wp) * 2 + hc) * 128 + g * 16;
        __builtin_amdgcn_global_load_lds(
            (const __attribute__((address_space(1))) void*)src,
            (__attribute__((address_space(3))) void*)(base + L * 16), 16, 0, 0);
      }
    }
  };
  // stage B tile for step s into dbuf slot sel (16KB, 2 gloads/thread)
  auto stageB = [&](int s, int sel) {
    const int tap = (s < 7) ? s : s - 7;
    const int hc  = (s >= 7);
    const char* bsrc = wt2 + (size_t)((tap * 2 + hc) * 2 + ft) * 16384;
    char* base = (char*)smem + B_BASE + sel * B_SLOT_B;
#pragma unroll
    for (int i = 0; i < 2; ++i) {
      const int L = i * 512 + tid;
      __builtin_amdgcn_global_load_lds(
          (const __attribute__((address_space(1))) void*)(bsrc + L * 16),
          (__attribute__((address_space(3))) void*)(base + L * 16), 16, 0, 0);
    }
  };
  // A-residency phase: taps {0,1} need rows {0,1}; taps {2..6} need rows {1,2}
  auto phase_of = [&](int s) { const int tap = (s < 7) ? s : s - 7; return (tap < 2) ? 1 : 2; };

  f32x4 acc[4][4] = {};

  // prologue: rows 0,1 of hc0 + B(0)
  stageA(0, 0, 0);
  stageA(1, 0, 1);
  stageB(0, 0);
  __syncthreads();

  int cur = 0;
  for (int s = 0; s < 14; ++s) {
    const int tap = (s < 7) ? s : s - 7;
    const int hc  = (s >= 7);

    // per-parity (row, dc, active)
    int row, dc, act;
    if (par == 0) {
      int kr, kc; even_tap(tap, row, dc, kr, kc);   // row = dr_e
      act = 1;
    } else {
      act = (tap <= 1) || (tap >= 5);
      row = (tap < 2) ? 1 : 2;                      // x-row offset from 2hp
      dc  = (tap == 0 || tap == 5) ? -1 : 0;
    }
    const int slot = (row == 1) ? 1 : 0;            // row0,2 -> slot0; row1 -> slot1
    const char* ab = (const char*)smem + slot * A_TILE_B;
    const char* bb = (const char*)smem + B_BASE + cur * B_SLOT_B;

    bf16x8 af[4][2], bfr[4][2];
    if (act) {
#pragma unroll
      for (int m = 0; m < 4; ++m) {
        const int wp = wr * 64 + m * 16 + l16 + dc + 1;   // absolute padded col
        const int key = wp & 7;
#pragma unroll
        for (int kk = 0; kk < 2; ++kk)
          af[m][kk] = *(const bf16x8*)(ab + wp * 128 + (((kk * 4 + lk) ^ key) * 16));
      }
#pragma unroll
      for (int fi = 0; fi < 4; ++fi) {
        const int fl = wc * 64 + fi * 16 + l16;
#pragma unroll
        for (int kk = 0; kk < 2; ++kk)
          bfr[fi][kk] = *(const bf16x8*)(bb + fl * 128 + (((kk * 4 + lk) ^ (fl & 7)) * 16));
      }
    }

    if (s + 1 < 14) stageB(s + 1, cur ^ 1);   // latency hides under MFMA

    if (act) {
#pragma unroll
      for (int m = 0; m < 4; ++m)
#pragma unroll
        for (int fi = 0; fi < 4; ++fi)
#pragma unroll
          for (int kk = 0; kk < 2; ++kk)
            acc[m][fi] = __builtin_amdgcn_mfma_f32_16x16x32_bf16(
                af[m][kk], bfr[fi][kk], acc[m][fi], 0, 0, 0);
    }

    if (s + 1 < 14) {
      const bool hcb = (s == 6);                          // hc0 -> hc1
      const bool phb = phase_of(s + 1) != phase_of(s);    // rows {0,1} -> {1,2}
      if (hcb || phb) {
        __syncthreads();              // all readers of outgoing A slots done
        if (hcb) { stageA(0, 1, 0); stageA(1, 1, 1); }
        else     { stageA(2, hc, 0); }                    // row2 -> slot0
      }
      __syncthreads();                // drains B(s+1) (+A if staged)
      cur ^= 1;
    }
  }

  // epilogue: + bias, relu, fp32.  D: col(f)=lane&15, row(w)=(lane>>4)*4+r
  const int hout = 2 * hp + par;
#pragma unroll
  for (int fi = 0; fi < 4; ++fi) {
    const int f = ft * 128 + wc * 64 + fi * 16 + l16;
    const float bv = bias[f];
#pragma unroll
    for (int m = 0; m < 4; ++m) {
      const int w = wr * 64 + m * 16 + lk * 4;
      float* o = out + (((size_t)(n * H_ + hout) * W_ + w) * F_ + f);
#pragma unroll
      for (int r = 0; r < 4; ++r) {
        float v = acc[m][fi][r] + bv;
        v = v > 0.f ? v : 0.f;
        o[(size_t)r * F_] = v;
      }
    }
  }
}

// ================= fallback (r6 kernel, proven) if ws too small =========
__device__ __forceinline__ void tap_info11(int t, int& dr, int& dc, int& kr, int& kc) {
  switch (t) {
    case 0:  dr = 0; dc = 0;  kr = 0; kc = 1; break;
    case 1:  dr = 0; dc = 1;  kr = 0; kc = 2; break;
    case 2:  dr = 1; dc = -1; kr = 1; kc = 0; break;
    case 3:  dr = 1; dc = 0;  kr = 1; kc = 1; break;
    case 4:  dr = 1; dc = 1;  kr = 1; kc = 2; break;
    case 5:  dr = 2; dc = 0;  kr = 2; kc = 1; break;
    case 6:  dr = 2; dc = 1;  kr = 2; kc = 2; break;
    case 7:  dr = 0; dc = -1; kr = 0; kc = 1; break;
    case 8:  dr = 0; dc = 0;  kr = 0; kc = 2; break;
    case 9:  dr = 1; dc = -1; kr = 2; kc = 1; break;
    default: dr = 1; dc = 0;  kr = 2; kc = 2; break;
  }
}

__global__ __launch_bounds__(256) void build_w_fb(
    const float* __restrict__ k, unsigned short* __restrict__ wt) {
  int tid = blockIdx.x * 256 + threadIdx.x;
  if (tid >= 11 * F_ * C_) return;
  int c = tid & 127;
  int f = (tid >> 7) & 255;
  int t = tid >> 15;
  int dr, dc, kr, kc;
  tap_info11(t, dr, dc, kr, kc);
  wt[tid] = (unsigned short)bf_bits(k[((kr * 3 + kc) * C_ + c) * F_ + f]);
}

__global__ __launch_bounds__(256, 3) void hconv_fb(
    const float* __restrict__ x,
    const unsigned short* __restrict__ wt,
    const float* __restrict__ bias,
    float* __restrict__ out) {
  __shared__ __align__(16) char smem_s[49152];
  const int tid = threadIdx.x;
  const int bid = (blockIdx.x & 7) * 1024 + (blockIdx.x >> 3);
  const int ft    = bid & 1;
  const int wtile = (bid >> 1) & 1;
  const int h     = (bid >> 2) & 127;
  const int n     = bid >> 9;
  const int f0 = ft * 128;
  const int w0 = wtile * 64;
  const int p  = h & 1;
  const int tap0   = p ? 7 : 0;
  const int nsteps = p ? 8 : 14;
  const int lane = tid & 63;
  const int wid  = tid >> 6;
  const int l16  = lane & 15;
  const int lk   = lane >> 4;
  const int awl = tid >> 2;
  const int ag2 = tid & 3;
  const int bfl   = tid >> 1;
  const int bhalf = tid & 1;
  float4 ar0, ar1, ar2, ar3;
  uint4  br0, br1, br2, br3;
  auto load_step = [&](int s) {
    const int tap = tap0 + (s >> 1);
    const int cc  = s & 1;
    int dr, dc, kr, kc;
    tap_info11(tap, dr, dc, kr, kc);
    const int hh = h + dr;
    const int wg = w0 + awl + dc;
    const bool av = (hh < H_) && (wg >= 0) && (wg < W_);
    if (av) {
      const float* ap = x + (((long)(n * H_ + hh) * W_ + wg) * C_ + cc * 64 + ag2 * 16);
      ar0 = *(const float4*)(ap);
      ar1 = *(const float4*)(ap + 4);
      ar2 = *(const float4*)(ap + 8);
      ar3 = *(const float4*)(ap + 12);
    } else {
      ar0 = ar1 = ar2 = ar3 = make_float4(0.f, 0.f, 0.f, 0.f);
    }
    const unsigned short* bp =
        wt + ((size_t)(tap * F_ + f0 + bfl) * C_ + cc * 64 + bhalf * 32);
    const uint4* bq = (const uint4*)bp;
    br0 = bq[0]; br1 = bq[1]; br2 = bq[2]; br3 = bq[3];
  };
  auto write_step = [&](int sel) {
    uint4 u0, u1;
    u0.x = pack2(ar0.x, ar0.y); u0.y = pack2(ar0.z, ar0.w);
    u0.z = pack2(ar1.x, ar1.y); u0.w = pack2(ar1.z, ar1.w);
    u1.x = pack2(ar2.x, ar2.y); u1.y = pack2(ar2.z, ar2.w);
    u1.z = pack2(ar3.x, ar3.y); u1.w = pack2(ar3.z, ar3.w);
    char* abase = (char*)smem_s + sel * 8192 + awl * 128;
    const int sw = awl & 7;
    *(uint4*)(abase + (((2 * ag2)     ^ sw) * 16)) = u0;
    *(uint4*)(abase + (((2 * ag2 + 1) ^ sw) * 16)) = u1;
    char* bbase = (char*)smem_s + 16384 + sel * 16384 + bfl * 128;
    const int sb = bfl & 7;
    *(uint4*)(bbase + (((bhalf * 4 + 0) ^ sb) * 16)) = br0;
    *(uint4*)(bbase + (((bhalf * 4 + 1) ^ sb) * 16)) = br1;
    *(uint4*)(bbase + (((bhalf * 4 + 2) ^ sb) * 16)) = br2;
    *(uint4*)(bbase + (((bhalf * 4 + 3) ^ sb) * 16)) = br3;
  };
  f32x4 acc[4][2] = {};
  load_step(0);
  write_step(0);
  load_step(1);
  __syncthreads();
  for (int s = 0; s < nsteps; ++s) {
    const int cur = s & 1;
    const char* ab = (const char*)smem_s + cur * 8192;
    const char* bb = (const char*)smem_s + 16384 + cur * 16384;
    bf16x8 af[4][2], bfr[2][2];
#pragma unroll
    for (int m = 0; m < 4; ++m)
#pragma unroll
      for (int kkk = 0; kkk < 2; ++kkk) {
        const int wl = m * 16 + l16;
        const int g  = (kkk * 4 + lk) ^ (wl & 7);
        af[m][kkk] = *(const bf16x8*)(ab + wl * 128 + g * 16);
      }
#pragma unroll
    for (int fi = 0; fi < 2; ++fi)
#pragma unroll
      for (int kkk = 0; kkk < 2; ++kkk) {
        const int fl = wid * 32 + fi * 16 + l16;
        const int g  = (kkk * 4 + lk) ^ (fl & 7);
        bfr[fi][kkk] = *(const bf16x8*)(bb + fl * 128 + g * 16);
      }
    if (s + 1 < nsteps) write_step(cur ^ 1);
    if (s + 2 < nsteps) load_step(s + 2);
#pragma unroll
    for (int m = 0; m < 4; ++m)
#pragma unroll
      for (int fi = 0; fi < 2; ++fi)
#pragma unroll
        for (int kkk = 0; kkk < 2; ++kkk)
          acc[m][fi] = __builtin_amdgcn_mfma_f32_16x16x32_bf16(
              af[m][kkk], bfr[fi][kkk], acc[m][fi], 0, 0, 0);
    __syncthreads();
  }
#pragma unroll
  for (int fi = 0; fi < 2; ++fi) {
    const int f = f0 + wid * 32 + fi * 16 + l16;
    const float bv = bias[f];
#pragma unroll
    for (int m = 0; m < 4; ++m) {
      const int w = w0 + m * 16 + lk * 4;
      float* o = out + (((size_t)(n * H_ + h) * W_ + w) * F_ + f);
#pragma unroll
      for (int r = 0; r < 4; ++r) {
        float v = acc[m][fi][r] + bv;
        v = v > 0.f ? v : 0.f;
        o[(size_t)r * F_] = v;
      }
    }
  }
}

extern "C" void kernel_launch(void* const* d_in, const int* in_sizes, int n_in,
                              void* d_out, int out_size, void* d_ws, size_t ws_size,
                              hipStream_t stream) {
  const float* x    = (const float*)d_in[0];
  const float* kern = (const float*)d_in[1];
  const float* bias = (const float*)d_in[2];
  float* out = (float*)d_out;

  const size_t XPAD_BYTES = (size_t)N_ * HP * WP * 256;        // 69,222,400
  const size_t WT2_BYTES  = (size_t)7 * 2 * 2 * 128 * 8 * 16;  // 458,752
  const int    SMEM_MAIN  = 2 * 16640 + 2 * 16384;             // 66,048

  if (ws_size >= XPAD_BYTES + WT2_BYTES) {
    char* xpadH = (char*)d_ws;
    char* wt2   = (char*)d_ws + XPAD_BYTES;
    (void)hipFuncSetAttribute((const void*)hconv_mfma,
                              hipFuncAttributeMaxDynamicSharedMemorySize,
                              SMEM_MAIN);
    prep_xpadH<<<16900, 256, 0, stream>>>(x, xpadH);
    prep_wt2<<<112, 256, 0, stream>>>(kern, wt2);
    hconv_mfma<<<N_ * 64 * 2, 512, SMEM_MAIN, stream>>>(xpadH, wt2, bias, out); // 2048
  } else {
    unsigned short* wt = (unsigned short*)d_ws;
    build_w_fb<<<(11 * F_ * C_ + 255) / 256, 256, 0, stream>>>(kern, wt);
    hconv_fb<<<N_ * H_ * 2 * 2, 256, 0, stream>>>(x, wt, bias, out);
  }
}

// Round 21
// 149.545 us; speedup vs baseline: 2.4527x; 2.4527x over previous
//
#include <hip/hip_runtime.h>

// Hex conv:  y[h,w,f] = relu( bias[f] + sum_taps x[h+dr, w+dc, c] * K[kr,kc][c][f] )
// even h (7 taps): (dr,dc,kr,kc)=(0,0,0,1)(0,1,0,2)(1,-1,1,0)(1,0,1,1)(1,1,1,2)(2,0,2,1)(2,1,2,2)
// odd  h (4 taps): (0,-1)K01 (0,0)K02 (1,-1)K21 (1,0)K22  -> weight tiles {0,1,5,6}
// x: (16,128,128,128) fp32 NHWC; K: (3,3,128,256) fp32 HWIO; bias: (256,) fp32. out fp32.
//
// FINAL = round 16/19 (best measured: 149.7-151.7 us, reproduced 3x).
// A = ONE 130-column halo tile per (x-row, hc) group (6 A-stages/even block),
// absolute-column XOR key, staged from pre-swizzled bf16 xpad via
// global_load_lds. B = dbuf 2x16KB, stage(s+1) issued before MFMA. 1
// barrier/step, 2 on A-boundary steps. LDS 49.4KB -> 3 blocks/CU.

#define N_  16
#define H_  128
#define W_  128
#define C_  128
#define F_  256
#define HP  130
#define WP  130

#define A_TILE_B   16640          // 130 rows x 128B
#define B_SLOT_B   16384
#define B_BASE     A_TILE_B       // B0 @16640, B1 @33024; total 49408

typedef short bf16x8 __attribute__((ext_vector_type(8)));
typedef float f32x4  __attribute__((ext_vector_type(4)));

__device__ __forceinline__ unsigned int bf_bits(float f) {
  unsigned int u = __float_as_uint(f);
  return (u + 0x7FFFu + ((u >> 16) & 1u)) >> 16;   // RNE fp32 -> bf16
}
__device__ __forceinline__ unsigned int pack2(float a, float b) {
  return bf_bits(a) | (bf_bits(b) << 16);
}

__device__ __forceinline__ void even_tap(int ti, int& dr, int& dc, int& kr, int& kc) {
  switch (ti) {
    case 0:  dr = 0; dc = 0;  kr = 0; kc = 1; break;
    case 1:  dr = 0; dc = 1;  kr = 0; kc = 2; break;
    case 2:  dr = 1; dc = -1; kr = 1; kc = 0; break;
    case 3:  dr = 1; dc = 0;  kr = 1; kc = 1; break;
    case 4:  dr = 1; dc = 1;  kr = 1; kc = 2; break;
    case 5:  dr = 2; dc = 0;  kr = 2; kc = 1; break;
    default: dr = 2; dc = 1;  kr = 2; kc = 2; break;
  }
}

// ---------- prep 1: pad + bf16 x, slot key = ABSOLUTE padded column (wp&7) ----
// xpadH pixel (n,hh,wp): 256B = [hc0:128B][hc1:128B]; slot g holds channels
// ((g ^ (wp&7))*8 .. +8) + hc*64 of x(n, hh, wp-1); zero outside image.
__global__ __launch_bounds__(256) void prep_xpadH(
    const float* __restrict__ x, char* __restrict__ xp) {
  long id = (long)blockIdx.x * 256 + threadIdx.x;   // exact 4,326,400 chunks
  const int g  = (int)(id & 7);
  const int hc = (int)((id >> 3) & 1);
  long pix = id >> 4;
  const int wp = (int)(pix % WP);
  long t = pix / WP;
  const int hh = (int)(t % HP);
  const int nn = (int)(t / HP);
  const int ww = wp - 1;
  uint4 o = make_uint4(0u, 0u, 0u, 0u);
  if (hh < H_ && ww >= 0 && ww < W_) {
    const float* s = x + (((long)(nn * H_ + hh) * W_ + ww) * C_ + hc * 64 + ((g ^ (wp & 7)) * 8));
    float4 a = *(const float4*)s;
    float4 b = *(const float4*)(s + 4);
    o.x = pack2(a.x, a.y); o.y = pack2(a.z, a.w);
    o.z = pack2(b.x, b.y); o.w = pack2(b.z, b.w);
  }
  *(uint4*)(xp + id * 16) = o;
}

// ---------- prep 2: weight tiles keyed (f&7) ----------
// wt2[ti 0..6][hc 0..1][ft 0..1] = 16KB: [f 0..127][slot 0..7][16B]
__global__ __launch_bounds__(256) void prep_wt2(
    const float* __restrict__ k, char* __restrict__ wt2) {
  int id = blockIdx.x * 256 + threadIdx.x;
  if (id >= 7 * 2 * 2 * 128 * 8) return;
  const int g  = id & 7;
  const int f  = (id >> 3) & 127;
  const int ft = (id >> 10) & 1;
  const int hc = (id >> 11) & 1;
  const int ti = id >> 12;
  int dr, dc, kr, kc;
  even_tap(ti, dr, dc, kr, kc);
  const int fg = ft * 128 + f;
  const int c0 = hc * 64 + (g ^ (f & 7)) * 8;
  float v[8];
#pragma unroll
  for (int j = 0; j < 8; ++j)
    v[j] = k[((size_t)(kr * 3 + kc) * C_ + (c0 + j)) * F_ + fg];
  uint4 o;
  o.x = pack2(v[0], v[1]); o.y = pack2(v[2], v[3]);
  o.z = pack2(v[4], v[5]); o.w = pack2(v[6], v[7]);
  *(uint4*)(wt2 + (size_t)id * 16) = o;
}

// ---------- main: 128(w) x 128(f), 4 waves, halo-A single + B dbuf ----------
__global__ __launch_bounds__(256, 3) void hconv_mfma(
    const char* __restrict__ xpadH,
    const char* __restrict__ wt2,
    const float* __restrict__ bias,
    float* __restrict__ out) {
  __shared__ __align__(16) char smem[49408];

  const int tid = threadIdx.x;
  const int bid = (blockIdx.x & 7) * 512 + (blockIdx.x >> 3);   // 4096 = 8*512
  const int ft = bid & 1;
  const int h  = (bid >> 1) & 127;
  const int n  = bid >> 8;
  const int p  = h & 1;
  const int nsteps = p ? 8 : 14;

  const int lane = tid & 63;
  const int wid  = tid >> 6;
  const int wr   = wid >> 1;
  const int wc   = wid & 1;
  const int l16  = lane & 15;
  const int lk   = lane >> 4;

  // step s -> (tap widx for B, dc, dr, hc) ; hc-outer ordering
  auto step_info = [&](int s, int& dc, int& widx, int& dr, int& hc) {
    if (p == 0) {
      hc = (s >= 7);
      const int tap = hc ? s - 7 : s;
      int kr, kc; even_tap(tap, dr, dc, kr, kc);
      widx = tap;
    } else {
      hc = (s >= 4);
      const int j = s & 3;
      dr = j >> 1;                       // 0,0,1,1
      dc = (j & 1) ? 0 : -1;             // -1,0,-1,0
      widx = (j == 0) ? 0 : (j == 1) ? 1 : (j == 2) ? 5 : 6;
    }
  };
  // A-tile id for step s: changes when (dr,hc) group changes
  auto tile_of = [&](int s) {
    if (p == 0) {
      const int hcp = (s >= 7);
      const int tap = hcp ? s - 7 : s;
      const int grp = (tap < 2) ? 0 : (tap < 5) ? 1 : 2;
      return hcp * 3 + grp;
    } else {
      return s >> 1;                     // 0..3
    }
  };

  // stage A halo tile (x-row h+dr, channel-half hc): 1040 16B chunks, linear dest
  auto stageA = [&](int tile) {
    int dr, hc;
    if (p == 0) { hc = tile >= 3; const int g3 = hc ? tile - 3 : tile; dr = g3; }
    else        { hc = tile >= 2; dr = tile & 1; }
    const long pixb = (long)(n * HP + (h + dr)) * WP;
#pragma unroll
    for (int i = 0; i < 5; ++i) {
      const int L = i * 256 + tid;
      if (L < 1040) {
        const int wp = L >> 3, g = L & 7;
        const char* src = xpadH + ((pixb + wp) * 2 + hc) * 128 + g * 16;
        __builtin_amdgcn_global_load_lds(
            (const __attribute__((address_space(1))) void*)src,
            (__attribute__((address_space(3))) void*)((char*)smem + L * 16), 16, 0, 0);
      }
    }
  };
  // stage B tile for step s into slot sel
  auto stageB = [&](int s, int sel) {
    int dc, widx, dr, hc; step_info(s, dc, widx, dr, hc);
    const char* bsrc = wt2 + (size_t)((widx * 2 + hc) * 2 + ft) * 16384;
    char* base = (char*)smem + B_BASE + sel * B_SLOT_B;
#pragma unroll
    for (int i = 0; i < 4; ++i) {
      const int L = i * 256 + tid;
      __builtin_amdgcn_global_load_lds(
          (const __attribute__((address_space(1))) void*)(bsrc + L * 16),
          (__attribute__((address_space(3))) void*)(base + L * 16), 16, 0, 0);
    }
  };

  f32x4 acc[4][4] = {};

  stageA(0);
  stageB(0, 0);
  __syncthreads();

  int cur = 0;
  for (int s = 0; s < nsteps; ++s) {
    int dc, widx, dr, hc; step_info(s, dc, widx, dr, hc);
    const char* ab = (const char*)smem;
    const char* bb = (const char*)smem + B_BASE + cur * B_SLOT_B;

    // fragment reads
    bf16x8 af[4][2], bfr[4][2];
#pragma unroll
    for (int m = 0; m < 4; ++m) {
      const int wp = wr * 64 + m * 16 + l16 + dc + 1;   // halo row (abs padded col)
      const int key = wp & 7;
#pragma unroll
      for (int kk = 0; kk < 2; ++kk)
        af[m][kk] = *(const bf16x8*)(ab + wp * 128 + (((kk * 4 + lk) ^ key) * 16));
    }
#pragma unroll
    for (int fi = 0; fi < 4; ++fi) {
      const int fl = wc * 64 + fi * 16 + l16;
#pragma unroll
      for (int kk = 0; kk < 2; ++kk)
        bfr[fi][kk] = *(const bf16x8*)(bb + fl * 128 + (((kk * 4 + lk) ^ (fl & 7)) * 16));
    }

    // issue next B stage early: latency hides under MFMA below
    if (s + 1 < nsteps) stageB(s + 1, cur ^ 1);

#pragma unroll
    for (int m = 0; m < 4; ++m)
#pragma unroll
      for (int fi = 0; fi < 4; ++fi)
#pragma unroll
        for (int kk = 0; kk < 2; ++kk)
          acc[m][fi] = __builtin_amdgcn_mfma_f32_16x16x32_bf16(
              af[m][kk], bfr[fi][kk], acc[m][fi], 0, 0, 0);

    if (s + 1 < nsteps) {
      if (tile_of(s + 1) != tile_of(s)) {
        __syncthreads();            // all A readers of current tile done
        stageA(tile_of(s + 1));     // overwrite the single A slot
      }
      __syncthreads();              // drains B(s+1) (+A if staged); visibility
      cur ^= 1;
    }
  }

  // epilogue: + bias, relu, fp32.  D: col(f)=lane&15, row(w)=(lane>>4)*4+r
#pragma unroll
  for (int fi = 0; fi < 4; ++fi) {
    const int f = ft * 128 + wc * 64 + fi * 16 + l16;
    const float bv = bias[f];
#pragma unroll
    for (int m = 0; m < 4; ++m) {
      const int w = wr * 64 + m * 16 + lk * 4;
      float* o = out + (((size_t)(n * H_ + h) * W_ + w) * F_ + f);
#pragma unroll
      for (int r = 0; r < 4; ++r) {
        float v = acc[m][fi][r] + bv;
        v = v > 0.f ? v : 0.f;
        o[(size_t)r * F_] = v;
      }
    }
  }
}

// ================= fallback (r6 kernel, proven) if ws too small =========
__device__ __forceinline__ void tap_info11(int t, int& dr, int& dc, int& kr, int& kc) {
  switch (t) {
    case 0:  dr = 0; dc = 0;  kr = 0; kc = 1; break;
    case 1:  dr = 0; dc = 1;  kr = 0; kc = 2; break;
    case 2:  dr = 1; dc = -1; kr = 1; kc = 0; break;
    case 3:  dr = 1; dc = 0;  kr = 1; kc = 1; break;
    case 4:  dr = 1; dc = 1;  kr = 1; kc = 2; break;
    case 5:  dr = 2; dc = 0;  kr = 2; kc = 1; break;
    case 6:  dr = 2; dc = 1;  kr = 2; kc = 2; break;
    case 7:  dr = 0; dc = -1; kr = 0; kc = 1; break;
    case 8:  dr = 0; dc = 0;  kr = 0; kc = 2; break;
    case 9:  dr = 1; dc = -1; kr = 2; kc = 1; break;
    default: dr = 1; dc = 0;  kr = 2; kc = 2; break;
  }
}

__global__ __launch_bounds__(256) void build_w_fb(
    const float* __restrict__ k, unsigned short* __restrict__ wt) {
  int tid = blockIdx.x * 256 + threadIdx.x;
  if (tid >= 11 * F_ * C_) return;
  int c = tid & 127;
  int f = (tid >> 7) & 255;
  int t = tid >> 15;
  int dr, dc, kr, kc;
  tap_info11(t, dr, dc, kr, kc);
  wt[tid] = (unsigned short)bf_bits(k[((kr * 3 + kc) * C_ + c) * F_ + f]);
}

__global__ __launch_bounds__(256, 3) void hconv_fb(
    const float* __restrict__ x,
    const unsigned short* __restrict__ wt,
    const float* __restrict__ bias,
    float* __restrict__ out) {
  __shared__ __align__(16) char smem_s[49152];
  const int tid = threadIdx.x;
  const int bid = (blockIdx.x & 7) * 1024 + (blockIdx.x >> 3);
  const int ft    = bid & 1;
  const int wtile = (bid >> 1) & 1;
  const int h     = (bid >> 2) & 127;
  const int n     = bid >> 9;
  const int f0 = ft * 128;
  const int w0 = wtile * 64;
  const int p  = h & 1;
  const int tap0   = p ? 7 : 0;
  const int nsteps = p ? 8 : 14;
  const int lane = tid & 63;
  const int wid  = tid >> 6;
  const int l16  = lane & 15;
  const int lk   = lane >> 4;
  const int awl = tid >> 2;
  const int ag2 = tid & 3;
  const int bfl   = tid >> 1;
  const int bhalf = tid & 1;
  float4 ar0, ar1, ar2, ar3;
  uint4  br0, br1, br2, br3;
  auto load_step = [&](int s) {
    const int tap = tap0 + (s >> 1);
    const int cc  = s & 1;
    int dr, dc, kr, kc;
    tap_info11(tap, dr, dc, kr, kc);
    const int hh = h + dr;
    const int wg = w0 + awl + dc;
    const bool av = (hh < H_) && (wg >= 0) && (wg < W_);
    if (av) {
      const float* ap = x + (((long)(n * H_ + hh) * W_ + wg) * C_ + cc * 64 + ag2 * 16);
      ar0 = *(const float4*)(ap);
      ar1 = *(const float4*)(ap + 4);
      ar2 = *(const float4*)(ap + 8);
      ar3 = *(const float4*)(ap + 12);
    } else {
      ar0 = ar1 = ar2 = ar3 = make_float4(0.f, 0.f, 0.f, 0.f);
    }
    const unsigned short* bp =
        wt + ((size_t)(tap * F_ + f0 + bfl) * C_ + cc * 64 + bhalf * 32);
    const uint4* bq = (const uint4*)bp;
    br0 = bq[0]; br1 = bq[1]; br2 = bq[2]; br3 = bq[3];
  };
  auto write_step = [&](int sel) {
    uint4 u0, u1;
    u0.x = pack2(ar0.x, ar0.y); u0.y = pack2(ar0.z, ar0.w);
    u0.z = pack2(ar1.x, ar1.y); u0.w = pack2(ar1.z, ar1.w);
    u1.x = pack2(ar2.x, ar2.y); u1.y = pack2(ar2.z, ar2.w);
    u1.z = pack2(ar3.x, ar3.y); u1.w = pack2(ar3.z, ar3.w);
    char* abase = (char*)smem_s + sel * 8192 + awl * 128;
    const int sw = awl & 7;
    *(uint4*)(abase + (((2 * ag2)     ^ sw) * 16)) = u0;
    *(uint4*)(abase + (((2 * ag2 + 1) ^ sw) * 16)) = u1;
    char* bbase = (char*)smem_s + 16384 + sel * 16384 + bfl * 128;
    const int sb = bfl & 7;
    *(uint4*)(bbase + (((bhalf * 4 + 0) ^ sb) * 16)) = br0;
    *(uint4*)(bbase + (((bhalf * 4 + 1) ^ sb) * 16)) = br1;
    *(uint4*)(bbase + (((bhalf * 4 + 2) ^ sb) * 16)) = br2;
    *(uint4*)(bbase + (((bhalf * 4 + 3) ^ sb) * 16)) = br3;
  };
  f32x4 acc[4][2] = {};
  load_step(0);
  write_step(0);
  load_step(1);
  __syncthreads();
  for (int s = 0; s < nsteps; ++s) {
    const int cur = s & 1;
    const char* ab = (const char*)smem_s + cur * 8192;
    const char* bb = (const char*)smem_s + 16384 + cur * 16384;
    bf16x8 af[4][2], bfr[2][2];
#pragma unroll
    for (int m = 0; m < 4; ++m)
#pragma unroll
      for (int kkk = 0; kkk < 2; ++kkk) {
        const int wl = m * 16 + l16;
        const int g  = (kkk * 4 + lk) ^ (wl & 7);
        af[m][kkk] = *(const bf16x8*)(ab + wl * 128 + g * 16);
      }
#pragma unroll
    for (int fi = 0; fi < 2; ++fi)
#pragma unroll
      for (int kkk = 0; kkk < 2; ++kkk) {
        const int fl = wid * 32 + fi * 16 + l16;
        const int g  = (kkk * 4 + lk) ^ (fl & 7);
        bfr[fi][kkk] = *(const bf16x8*)(bb + fl * 128 + g * 16);
      }
    if (s + 1 < nsteps) write_step(cur ^ 1);
    if (s + 2 < nsteps) load_step(s + 2);
#pragma unroll
    for (int m = 0; m < 4; ++m)
#pragma unroll
      for (int fi = 0; fi < 2; ++fi)
#pragma unroll
        for (int kkk = 0; kkk < 2; ++kkk)
          acc[m][fi] = __builtin_amdgcn_mfma_f32_16x16x32_bf16(
              af[m][kkk], bfr[fi][kkk], acc[m][fi], 0, 0, 0);
    __syncthreads();
  }
#pragma unroll
  for (int fi = 0; fi < 2; ++fi) {
    const int f = f0 + wid * 32 + fi * 16 + l16;
    const float bv = bias[f];
#pragma unroll
    for (int m = 0; m < 4; ++m) {
      const int w = w0 + m * 16 + lk * 4;
      float* o = out + (((size_t)(n * H_ + h) * W_ + w) * F_ + f);
#pragma unroll
      for (int r = 0; r < 4; ++r) {
        float v = acc[m][fi][r] + bv;
        v = v > 0.f ? v : 0.f;
        o[(size_t)r * F_] = v;
      }
    }
  }
}

extern "C" void kernel_launch(void* const* d_in, const int* in_sizes, int n_in,
                              void* d_out, int out_size, void* d_ws, size_t ws_size,
                              hipStream_t stream) {
  const float* x    = (const float*)d_in[0];
  const float* kern = (const float*)d_in[1];
  const float* bias = (const float*)d_in[2];
  float* out = (float*)d_out;

  const size_t XPAD_BYTES = (size_t)N_ * HP * WP * 256;        // 69,222,400
  const size_t WT2_BYTES  = (size_t)7 * 2 * 2 * 128 * 8 * 16;  // 458,752

  if (ws_size >= XPAD_BYTES + WT2_BYTES) {
    char* xpadH = (char*)d_ws;
    char* wt2   = (char*)d_ws + XPAD_BYTES;
    prep_xpadH<<<16900, 256, 0, stream>>>(x, xpadH);
    prep_wt2<<<112, 256, 0, stream>>>(kern, wt2);
    hconv_mfma<<<N_ * H_ * 2, 256, 0, stream>>>(xpadH, wt2, bias, out);  // 4096
  } else {
    unsigned short* wt = (unsigned short*)d_ws;
    build_w_fb<<<(11 * F_ * C_ + 255) / 256, 256, 0, stream>>>(kern, wt);
    hconv_fb<<<N_ * H_ * 2 * 2, 256, 0, stream>>>(x, wt, bias, out);
  }
}